// Round 1
// baseline (810.946 us; speedup 1.0000x reference)
//
#include <hip/hip_runtime.h>

// ---------------------------------------------------------------------------
// MoE FFN: SEQ=8192, IN_DIM=1024, HID=2048, 8 experts, topk=2, gelu(tanh) gate
// Plan: cast weights/input to bf16 once per call, sort dispatch slots by
// expert (single-block routing kernel, atomic-free), grouped MFMA GEMMs:
//   GEMM1: act = gelu(x@Wg^T) * (x@Wu^T)   (fused, bf16 out)
//   GEMM2: out += w * (act @ Wd)           (Wd pre-transposed, fp32 atomics)
// ---------------------------------------------------------------------------

#define SEQ 8192
#define IN_DIM 1024
#define HID 2048
#define NEXP 8
#define TOPK 2
#define NSLOT (SEQ * TOPK)

#define BM 128
#define BN 128
#define BK 64
#define MAX_TILES 136

typedef unsigned short ushort_t;
typedef __bf16 bf16x8 __attribute__((ext_vector_type(8)));
typedef float f32x4 __attribute__((ext_vector_type(4)));

// fp32 -> bf16 round-to-nearest-even (inputs are finite; no NaN path needed)
__device__ __forceinline__ ushort_t f2bf(float f) {
    union { float f; unsigned u; } v;
    v.f = f;
    unsigned r = v.u + 0x7FFFu + ((v.u >> 16) & 1u);
    return (ushort_t)(r >> 16);
}

// gelu tanh-approx:  x * sigmoid(2u),  u = sqrt(2/pi)*(x + 0.044715 x^3)
__device__ __forceinline__ float gelu_tanh(float x) {
    float u = 0.7978845608028654f * x * (1.0f + 0.044715f * x * x);
    return x / (1.0f + __expf(-2.0f * u));
}

// async global->LDS, 16B per lane; LDS base MUST be wave-uniform (HW adds lane*16)
__device__ __forceinline__ void async16(const void* g, void* l) {
    __builtin_amdgcn_global_load_lds(
        (const __attribute__((address_space(1))) unsigned int*)g,
        (__attribute__((address_space(3))) unsigned int*)l, 16, 0, 0);
}

// ---------------------------------------------------------------------------
__global__ void cast_bf16_kernel(const float* __restrict__ in,
                                 ushort_t* __restrict__ out, int n) {
    int i = (blockIdx.x * blockDim.x + threadIdx.x) * 4;
    if (i >= n) return;
    float4 v = *(const float4*)(in + i);
    union { ushort_t u[4]; uint2 v; } o;
    o.u[0] = f2bf(v.x); o.u[1] = f2bf(v.y);
    o.u[2] = f2bf(v.z); o.u[3] = f2bf(v.w);
    *(uint2*)(out + i) = o.v;
}

// down_proj [8][2048][1024] fp32 -> [8][1024][2048] bf16 (so GEMM2 is K-contiguous)
__global__ void transpose_cast_kernel(const float* __restrict__ in,
                                      ushort_t* __restrict__ out) {
    __shared__ float tile[32][33];
    int e = blockIdx.z;
    int d0 = blockIdx.x * 32, h0 = blockIdx.y * 32;
    int tx = threadIdx.x & 31, ty = threadIdx.x >> 5;  // 32 x 8
    const float* src = in + (size_t)e * HID * IN_DIM;
    for (int j = 0; j < 32; j += 8)
        tile[ty + j][tx] = src[(size_t)(h0 + ty + j) * IN_DIM + d0 + tx];
    __syncthreads();
    ushort_t* dst = out + (size_t)e * IN_DIM * HID;
    for (int j = 0; j < 32; j += 8)
        dst[(size_t)(d0 + ty + j) * HID + h0 + tx] = f2bf(tile[tx][ty + j]);
}

// ---------------------------------------------------------------------------
// Routing: single block, 256 threads. Counts per expert, exclusive prefix over
// threads (atomic-free), emits sorted (token,weight) per dispatch position,
// expert offsets meta[0..8], tile count meta[16], tile list meta[32+2i..]
__global__ void route_kernel(const int* __restrict__ sel,
                             const float* __restrict__ wts,
                             int* __restrict__ meta,
                             int* __restrict__ stok,
                             float* __restrict__ sw) {
    __shared__ int lc[256][NEXP];   // 8 KB
    __shared__ int tot[NEXP];
    __shared__ int s_off[NEXP + 1];
    int t = threadIdx.x;
    int cnt[NEXP];
#pragma unroll
    for (int e = 0; e < NEXP; e++) cnt[e] = 0;
    int base = t * (NSLOT / 256);
    for (int i = 0; i < NSLOT / 256; i++) cnt[sel[base + i]]++;
#pragma unroll
    for (int e = 0; e < NEXP; e++) lc[t][e] = cnt[e];
    __syncthreads();
    if (t < NEXP) {
        int run = 0;
        for (int i = 0; i < 256; i++) { int v = lc[i][t]; lc[i][t] = run; run += v; }
        tot[t] = run;
    }
    __syncthreads();
    if (t == 0) {
        int o = 0;
        for (int e = 0; e < NEXP; e++) { s_off[e] = o; o += tot[e]; }
        s_off[NEXP] = o;
        for (int e = 0; e <= NEXP; e++) meta[e] = s_off[e];
        int nt = 0;
        for (int e = 0; e < NEXP; e++) {
            int c = s_off[e + 1] - s_off[e];
            int m = (c + BM - 1) / BM;
            for (int i = 0; i < m; i++) { meta[32 + 2 * nt] = e; meta[33 + 2 * nt] = i; nt++; }
        }
        meta[16] = nt;
    }
    __syncthreads();
    int cur[NEXP];
#pragma unroll
    for (int e = 0; e < NEXP; e++) cur[e] = s_off[e] + lc[t][e];
    for (int i = 0; i < NSLOT / 256; i++) {
        int slot = base + i;
        int e = sel[slot];
        int pos = cur[e]++;
        stok[pos] = slot >> 1;     // token id (slot = token*TOPK + k)
        sw[pos] = wts[slot];
    }
}

// ---------------------------------------------------------------------------
// GEMM1: for each sorted dispatch row, h = x@Wu^T, g = x@Wg^T, act = gelu(g)*h
// A gathered by token id. 128x128 tile, BK=64, 4 waves in 2x2, 16x16x32 MFMA.
__global__ __launch_bounds__(256) void gemm1_kernel(
    const ushort_t* __restrict__ X,     // [SEQ][IN_DIM] bf16
    const ushort_t* __restrict__ U,     // [NEXP][HID][IN_DIM] bf16
    const ushort_t* __restrict__ G,     // [NEXP][HID][IN_DIM] bf16
    const int* __restrict__ meta,
    const int* __restrict__ stok,
    ushort_t* __restrict__ act) {       // [NSLOT][HID] bf16
    __shared__ __align__(16) ushort_t XT[BM * BK];
    __shared__ __align__(16) ushort_t UT[BN * BK];
    __shared__ __align__(16) ushort_t GT[BN * BK];
    __shared__ int s_tok[BM];

    int tile = blockIdx.y;
    if (tile >= meta[16]) return;
    int e = meta[32 + 2 * tile];
    int mt = meta[33 + 2 * tile];
    int off = meta[e];
    int cnt = meta[e + 1] - off;
    int m0 = mt * BM;
    int n0 = blockIdx.x * BN;

    int tid = threadIdx.x;
    if (tid < BM) {
        int r = m0 + tid;
        if (r >= cnt) r = cnt - 1;          // clamp pad rows to a valid token
        s_tok[tid] = stok[off + r];
    }
    __syncthreads();

    int lane = tid & 63;
    int w = tid >> 6;                        // wave 0..3
    int wr = w >> 1, wc = w & 1;             // 2x2 wave grid, 64x64 each
    int srow = lane >> 3;                    // staging: row-in-group 0..7
    int schunk = lane & 7;                   // staging: 16B chunk 0..7

    const ushort_t* Ue = U + ((size_t)e * HID + n0) * IN_DIM;
    const ushort_t* Ge = G + ((size_t)e * HID + n0) * IN_DIM;

    // hoisted staging source pointers (row fixed, k advances)
    const ushort_t* xp[4];
    const ushort_t* up[4];
    const ushort_t* gp[4];
    ushort_t* ldst[4];
#pragma unroll
    for (int i = 0; i < 4; i++) {
        int r = w * 32 + i * 8 + srow;
        xp[i] = X + (size_t)s_tok[r] * IN_DIM + schunk * 8;
        up[i] = Ue + (size_t)r * IN_DIM + schunk * 8;
        gp[i] = Ge + (size_t)r * IN_DIM + schunk * 8;
        ldst[i] = (ushort_t*)((w * 32 + i * 8) * BK);  // offset only; add base later
    }

    f32x4 accH[4][4], accG[4][4];
#pragma unroll
    for (int mi = 0; mi < 4; mi++)
#pragma unroll
        for (int ni = 0; ni < 4; ni++) {
            accH[mi][ni] = (f32x4){0.f, 0.f, 0.f, 0.f};
            accG[mi][ni] = (f32x4){0.f, 0.f, 0.f, 0.f};
        }

    for (int k0 = 0; k0 < IN_DIM; k0 += BK) {
#pragma unroll
        for (int i = 0; i < 4; i++) {
            int lo = (w * 32 + i * 8) * BK;  // wave-uniform LDS base (elements)
            async16(xp[i] + k0, &XT[lo]);
            async16(up[i] + k0, &UT[lo]);
            async16(gp[i] + k0, &GT[lo]);
        }
        __syncthreads();
#pragma unroll
        for (int kk = 0; kk < BK; kk += 32) {
            int ko = kk + ((lane >> 4) << 3);
            bf16x8 a[4], bu[4], bg[4];
#pragma unroll
            for (int i = 0; i < 4; i++) {
                a[i]  = *(const bf16x8*)&XT[(wr * 64 + i * 16 + (lane & 15)) * BK + ko];
                bu[i] = *(const bf16x8*)&UT[(wc * 64 + i * 16 + (lane & 15)) * BK + ko];
                bg[i] = *(const bf16x8*)&GT[(wc * 64 + i * 16 + (lane & 15)) * BK + ko];
            }
#pragma unroll
            for (int mi = 0; mi < 4; mi++)
#pragma unroll
                for (int ni = 0; ni < 4; ni++) {
                    accH[mi][ni] = __builtin_amdgcn_mfma_f32_16x16x32_bf16(
                        a[mi], bu[ni], accH[mi][ni], 0, 0, 0);
                    accG[mi][ni] = __builtin_amdgcn_mfma_f32_16x16x32_bf16(
                        a[mi], bg[ni], accG[mi][ni], 0, 0, 0);
                }
        }
        __syncthreads();
    }

    // epilogue: act = gelu(g)*h, bf16 store. C/D: col=lane&15, row=(lane>>4)*4+r
#pragma unroll
    for (int mi = 0; mi < 4; mi++) {
#pragma unroll
        for (int r = 0; r < 4; r++) {
            int row_local = wr * 64 + mi * 16 + (lane >> 4) * 4 + r;
            int grow = m0 + row_local;
            if (grow >= cnt) continue;
            size_t orow = (size_t)(off + grow) * HID + n0 + wc * 64;
#pragma unroll
            for (int ni = 0; ni < 4; ni++) {
                float h = accH[mi][ni][r];
                float g = accG[mi][ni][r];
                act[orow + ni * 16 + (lane & 15)] = f2bf(gelu_tanh(g) * h);
            }
        }
    }
}

// ---------------------------------------------------------------------------
// GEMM2: out[token] += w * (act @ Wd),  Wd pre-transposed to [e][IN_DIM][HID]
__global__ __launch_bounds__(256) void gemm2_kernel(
    const ushort_t* __restrict__ act,   // [NSLOT][HID] bf16
    const ushort_t* __restrict__ DT,    // [NEXP][IN_DIM][HID] bf16
    const int* __restrict__ meta,
    const int* __restrict__ stok,
    const float* __restrict__ sw,
    float* __restrict__ out) {          // [SEQ][IN_DIM] fp32 (pre-zeroed)
    __shared__ __align__(16) ushort_t AT[BM * BK];
    __shared__ __align__(16) ushort_t BT[BN * BK];

    int tile = blockIdx.y;
    if (tile >= meta[16]) return;
    int e = meta[32 + 2 * tile];
    int mt = meta[33 + 2 * tile];
    int off = meta[e];
    int cnt = meta[e + 1] - off;
    int m0 = mt * BM;
    int n0 = blockIdx.x * BN;            // grid.x = IN_DIM/BN = 8

    int tid = threadIdx.x;
    int lane = tid & 63;
    int w = tid >> 6;
    int wr = w >> 1, wc = w & 1;
    int srow = lane >> 3;
    int schunk = lane & 7;

    const ushort_t* Ae = act + (size_t)off * HID;
    const ushort_t* Be = DT + ((size_t)e * IN_DIM + n0) * HID;

    const ushort_t* ap[4];
    const ushort_t* bp[4];
#pragma unroll
    for (int i = 0; i < 4; i++) {
        int r = w * 32 + i * 8 + srow;
        int ar = m0 + r; if (ar >= cnt) ar = cnt - 1;   // clamp to valid rows
        ap[i] = Ae + (size_t)ar * HID + schunk * 8;
        bp[i] = Be + (size_t)r * HID + schunk * 8;
    }

    f32x4 acc[4][4];
#pragma unroll
    for (int mi = 0; mi < 4; mi++)
#pragma unroll
        for (int ni = 0; ni < 4; ni++) acc[mi][ni] = (f32x4){0.f, 0.f, 0.f, 0.f};

    for (int k0 = 0; k0 < HID; k0 += BK) {
#pragma unroll
        for (int i = 0; i < 4; i++) {
            int lo = (w * 32 + i * 8) * BK;
            async16(ap[i] + k0, &AT[lo]);
            async16(bp[i] + k0, &BT[lo]);
        }
        __syncthreads();
#pragma unroll
        for (int kk = 0; kk < BK; kk += 32) {
            int ko = kk + ((lane >> 4) << 3);
            bf16x8 a[4], b[4];
#pragma unroll
            for (int i = 0; i < 4; i++) {
                a[i] = *(const bf16x8*)&AT[(wr * 64 + i * 16 + (lane & 15)) * BK + ko];
                b[i] = *(const bf16x8*)&BT[(wc * 64 + i * 16 + (lane & 15)) * BK + ko];
            }
#pragma unroll
            for (int mi = 0; mi < 4; mi++)
#pragma unroll
                for (int ni = 0; ni < 4; ni++)
                    acc[mi][ni] = __builtin_amdgcn_mfma_f32_16x16x32_bf16(
                        a[mi], b[ni], acc[mi][ni], 0, 0, 0);
        }
        __syncthreads();
    }

    // epilogue: weighted atomic combine into out[token]
#pragma unroll
    for (int mi = 0; mi < 4; mi++) {
#pragma unroll
        for (int r = 0; r < 4; r++) {
            int row_local = wr * 64 + mi * 16 + (lane >> 4) * 4 + r;
            int grow = m0 + row_local;
            if (grow >= cnt) continue;
            int pos = off + grow;
            int tok = stok[pos];
            float wgt = sw[pos];
            float* orow = out + (size_t)tok * IN_DIM + n0 + wc * 64;
#pragma unroll
            for (int ni = 0; ni < 4; ni++)
                atomicAdd(&orow[ni * 16 + (lane & 15)], wgt * acc[mi][ni][r]);
        }
    }
}

// ---------------------------------------------------------------------------
extern "C" void kernel_launch(void* const* d_in, const int* in_sizes, int n_in,
                              void* d_out, int out_size, void* d_ws, size_t ws_size,
                              hipStream_t stream) {
    const float* inp  = (const float*)d_in[0];
    const float* wts  = (const float*)d_in[1];
    const float* up   = (const float*)d_in[2];
    const float* gate = (const float*)d_in[3];
    const float* down = (const float*)d_in[4];
    const int*   sel  = (const int*)d_in[5];
    float* out = (float*)d_out;

    // workspace layout (bytes):
    //   inp_bf  [SEQ*IN_DIM]         @ 0          (16,777,216)
    //   up_bf   [NEXP*HID*IN_DIM]    @ 16777216   (33,554,432)
    //   gate_bf                      @ 50331648   (33,554,432)
    //   downT_bf [NEXP*IN_DIM*HID]   @ 83886080   (33,554,432)
    //   act_bf  [NSLOT*HID]          @ 117440512  (67,108,864)
    //   stok    [NSLOT] int          @ 184549376  (65,536)
    //   sw      [NSLOT] float        @ 184614912  (65,536)
    //   meta    ints                 @ 184680448  (4,096)     total ~176 MB
    char* ws = (char*)d_ws;
    ushort_t* inp_bf  = (ushort_t*)(ws);
    ushort_t* up_bf   = (ushort_t*)(ws + 16777216);
    ushort_t* gate_bf = (ushort_t*)(ws + 50331648);
    ushort_t* down_bf = (ushort_t*)(ws + 83886080);
    ushort_t* act     = (ushort_t*)(ws + 117440512);
    int*      stok    = (int*)(ws + 184549376);
    float*    sw      = (float*)(ws + 184614912);
    int*      meta    = (int*)(ws + 184680448);

    hipMemsetAsync(d_out, 0, (size_t)SEQ * IN_DIM * sizeof(float), stream);

    cast_bf16_kernel<<<(SEQ * IN_DIM) / 1024, 256, 0, stream>>>(inp, inp_bf, SEQ * IN_DIM);
    cast_bf16_kernel<<<(NEXP * HID * IN_DIM) / 1024, 256, 0, stream>>>(up, up_bf, NEXP * HID * IN_DIM);
    cast_bf16_kernel<<<(NEXP * HID * IN_DIM) / 1024, 256, 0, stream>>>(gate, gate_bf, NEXP * HID * IN_DIM);
    transpose_cast_kernel<<<dim3(IN_DIM / 32, HID / 32, NEXP), 256, 0, stream>>>(down, down_bf);
    route_kernel<<<1, 256, 0, stream>>>(sel, wts, meta, stok, sw);
    gemm1_kernel<<<dim3(HID / BN, MAX_TILES, 1), 256, 0, stream>>>(inp_bf, up_bf, gate_bf, meta, stok, act);
    gemm2_kernel<<<dim3(IN_DIM / BN, MAX_TILES, 1), 256, 0, stream>>>(act, down_bf, meta, stok, sw, out);
}

// Round 2
// 760.352 us; speedup vs baseline: 1.0665x; 1.0665x over previous
//
#include <hip/hip_runtime.h>

// ---------------------------------------------------------------------------
// MoE FFN: SEQ=8192, IN_DIM=1024, HID=2048, 8 experts, topk=2, gelu(tanh) gate
// R2: XOR-swizzled LDS staging (global_load_lds forces base+lane*16 writes, so
// we permute the *global source chunk* per lane: lane(srow,schunk) fetches
// chunk schunk^srow; readers index chunk c^(row&7)). Kills the 16-way bank
// conflict from the 128 B row stride (R1: 3.86e7 conflict cycles on gemm1).
// ---------------------------------------------------------------------------

#define SEQ 8192
#define IN_DIM 1024
#define HID 2048
#define NEXP 8
#define TOPK 2
#define NSLOT (SEQ * TOPK)

#define BM 128
#define BN 128
#define BK 64
#define MAX_TILES 136

typedef unsigned short ushort_t;
typedef __bf16 bf16x8 __attribute__((ext_vector_type(8)));
typedef float f32x4 __attribute__((ext_vector_type(4)));

__device__ __forceinline__ ushort_t f2bf(float f) {
    union { float f; unsigned u; } v;
    v.f = f;
    unsigned r = v.u + 0x7FFFu + ((v.u >> 16) & 1u);
    return (ushort_t)(r >> 16);
}

__device__ __forceinline__ float gelu_tanh(float x) {
    float u = 0.7978845608028654f * x * (1.0f + 0.044715f * x * x);
    return x / (1.0f + __expf(-2.0f * u));
}

__device__ __forceinline__ void async16(const void* g, void* l) {
    __builtin_amdgcn_global_load_lds(
        (const __attribute__((address_space(1))) unsigned int*)g,
        (__attribute__((address_space(3))) unsigned int*)l, 16, 0, 0);
}

// ---------------------------------------------------------------------------
__global__ void cast_bf16_kernel(const float* __restrict__ in,
                                 ushort_t* __restrict__ out, int n) {
    int i = (blockIdx.x * blockDim.x + threadIdx.x) * 4;
    if (i >= n) return;
    float4 v = *(const float4*)(in + i);
    union { ushort_t u[4]; uint2 v; } o;
    o.u[0] = f2bf(v.x); o.u[1] = f2bf(v.y);
    o.u[2] = f2bf(v.z); o.u[3] = f2bf(v.w);
    *(uint2*)(out + i) = o.v;
}

// down_proj [8][2048][1024] fp32 -> [8][1024][2048] bf16
__global__ void transpose_cast_kernel(const float* __restrict__ in,
                                      ushort_t* __restrict__ out) {
    __shared__ float tile[32][33];
    int e = blockIdx.z;
    int d0 = blockIdx.x * 32, h0 = blockIdx.y * 32;
    int tx = threadIdx.x & 31, ty = threadIdx.x >> 5;  // 32 x 8
    const float* src = in + (size_t)e * HID * IN_DIM;
    for (int j = 0; j < 32; j += 8)
        tile[ty + j][tx] = src[(size_t)(h0 + ty + j) * IN_DIM + d0 + tx];
    __syncthreads();
    ushort_t* dst = out + (size_t)e * IN_DIM * HID;
    for (int j = 0; j < 32; j += 8)
        dst[(size_t)(d0 + ty + j) * HID + h0 + tx] = f2bf(tile[tx][ty + j]);
}

// ---------------------------------------------------------------------------
__global__ void route_kernel(const int* __restrict__ sel,
                             const float* __restrict__ wts,
                             int* __restrict__ meta,
                             int* __restrict__ stok,
                             float* __restrict__ sw) {
    __shared__ int lc[256][NEXP];
    __shared__ int tot[NEXP];
    __shared__ int s_off[NEXP + 1];
    int t = threadIdx.x;
    int cnt[NEXP];
#pragma unroll
    for (int e = 0; e < NEXP; e++) cnt[e] = 0;
    int base = t * (NSLOT / 256);
    for (int i = 0; i < NSLOT / 256; i++) cnt[sel[base + i]]++;
#pragma unroll
    for (int e = 0; e < NEXP; e++) lc[t][e] = cnt[e];
    __syncthreads();
    if (t < NEXP) {
        int run = 0;
        for (int i = 0; i < 256; i++) { int v = lc[i][t]; lc[i][t] = run; run += v; }
        tot[t] = run;
    }
    __syncthreads();
    if (t == 0) {
        int o = 0;
        for (int e = 0; e < NEXP; e++) { s_off[e] = o; o += tot[e]; }
        s_off[NEXP] = o;
        for (int e = 0; e <= NEXP; e++) meta[e] = s_off[e];
        int nt = 0;
        for (int e = 0; e < NEXP; e++) {
            int c = s_off[e + 1] - s_off[e];
            int m = (c + BM - 1) / BM;
            for (int i = 0; i < m; i++) { meta[32 + 2 * nt] = e; meta[33 + 2 * nt] = i; nt++; }
        }
        meta[16] = nt;
    }
    __syncthreads();
    int cur[NEXP];
#pragma unroll
    for (int e = 0; e < NEXP; e++) cur[e] = s_off[e] + lc[t][e];
    for (int i = 0; i < NSLOT / 256; i++) {
        int slot = base + i;
        int e = sel[slot];
        int pos = cur[e]++;
        stok[pos] = slot >> 1;
        sw[pos] = wts[slot];
    }
}

// ---------------------------------------------------------------------------
// GEMM1: act = gelu(x@Wg^T) * (x@Wu^T), rows gathered by sorted token id.
__global__ __launch_bounds__(256) void gemm1_kernel(
    const ushort_t* __restrict__ X,
    const ushort_t* __restrict__ U,
    const ushort_t* __restrict__ G,
    const int* __restrict__ meta,
    const int* __restrict__ stok,
    ushort_t* __restrict__ act) {
    __shared__ __align__(16) ushort_t XT[BM * BK];
    __shared__ __align__(16) ushort_t UT[BN * BK];
    __shared__ __align__(16) ushort_t GT[BN * BK];
    __shared__ int s_tok[BM];

    int tile = blockIdx.y;
    if (tile >= meta[16]) return;
    int e = meta[32 + 2 * tile];
    int mt = meta[33 + 2 * tile];
    int off = meta[e];
    int cnt = meta[e + 1] - off;
    int m0 = mt * BM;
    int n0 = blockIdx.x * BN;

    int tid = threadIdx.x;
    if (tid < BM) {
        int r = m0 + tid;
        if (r >= cnt) r = cnt - 1;
        s_tok[tid] = stok[off + r];
    }
    __syncthreads();

    int lane = tid & 63;
    int w = tid >> 6;
    int wr = w >> 1, wc = w & 1;
    int srow = lane >> 3;        // 0..7 : row within the wave's 8-row group
    int schunk = lane & 7;       // 0..7 : 16B chunk slot in LDS (fixed by HW)
    int gchunk = schunk ^ srow;  // 0..7 : which global chunk this lane fetches

    const ushort_t* Ue = U + ((size_t)e * HID + n0) * IN_DIM;
    const ushort_t* Ge = G + ((size_t)e * HID + n0) * IN_DIM;

    const ushort_t* xp[4];
    const ushort_t* up[4];
    const ushort_t* gp[4];
#pragma unroll
    for (int i = 0; i < 4; i++) {
        int r = w * 32 + i * 8 + srow;
        xp[i] = X + (size_t)s_tok[r] * IN_DIM + gchunk * 8;
        up[i] = Ue + (size_t)r * IN_DIM + gchunk * 8;
        gp[i] = Ge + (size_t)r * IN_DIM + gchunk * 8;
    }

    f32x4 accH[4][4], accG[4][4];
#pragma unroll
    for (int mi = 0; mi < 4; mi++)
#pragma unroll
        for (int ni = 0; ni < 4; ni++) {
            accH[mi][ni] = (f32x4){0.f, 0.f, 0.f, 0.f};
            accG[mi][ni] = (f32x4){0.f, 0.f, 0.f, 0.f};
        }

    int r4 = lane & 15;
    int q = lane >> 4;           // quad-group 0..3
    int sw7 = r4 & 7;            // row&7 for swizzled read

    for (int k0 = 0; k0 < IN_DIM; k0 += BK) {
#pragma unroll
        for (int i = 0; i < 4; i++) {
            int lo = (w * 32 + i * 8) * BK;
            async16(xp[i] + k0, &XT[lo]);
            async16(up[i] + k0, &UT[lo]);
            async16(gp[i] + k0, &GT[lo]);
        }
        __syncthreads();
#pragma unroll
        for (int kk = 0; kk < BK; kk += 32) {
            int c = (kk >> 3) + q;               // chunk index 0..7
            int cs = ((c ^ sw7) << 3);           // swizzled element offset
            bf16x8 a[4], bu[4], bg[4];
#pragma unroll
            for (int i = 0; i < 4; i++) {
                a[i]  = *(const bf16x8*)&XT[(wr * 64 + i * 16 + r4) * BK + cs];
                bu[i] = *(const bf16x8*)&UT[(wc * 64 + i * 16 + r4) * BK + cs];
                bg[i] = *(const bf16x8*)&GT[(wc * 64 + i * 16 + r4) * BK + cs];
            }
#pragma unroll
            for (int mi = 0; mi < 4; mi++)
#pragma unroll
                for (int ni = 0; ni < 4; ni++) {
                    accH[mi][ni] = __builtin_amdgcn_mfma_f32_16x16x32_bf16(
                        a[mi], bu[ni], accH[mi][ni], 0, 0, 0);
                    accG[mi][ni] = __builtin_amdgcn_mfma_f32_16x16x32_bf16(
                        a[mi], bg[ni], accG[mi][ni], 0, 0, 0);
                }
        }
        __syncthreads();
    }

#pragma unroll
    for (int mi = 0; mi < 4; mi++) {
#pragma unroll
        for (int r = 0; r < 4; r++) {
            int row_local = wr * 64 + mi * 16 + (lane >> 4) * 4 + r;
            int grow = m0 + row_local;
            if (grow >= cnt) continue;
            size_t orow = (size_t)(off + grow) * HID + n0 + wc * 64;
#pragma unroll
            for (int ni = 0; ni < 4; ni++) {
                float h = accH[mi][ni][r];
                float g = accG[mi][ni][r];
                act[orow + ni * 16 + (lane & 15)] = f2bf(gelu_tanh(g) * h);
            }
        }
    }
}

// ---------------------------------------------------------------------------
// GEMM2: out[token] += w * (act @ Wd^T-pretransposed)
__global__ __launch_bounds__(256) void gemm2_kernel(
    const ushort_t* __restrict__ act,
    const ushort_t* __restrict__ DT,
    const int* __restrict__ meta,
    const int* __restrict__ stok,
    const float* __restrict__ sw,
    float* __restrict__ out) {
    __shared__ __align__(16) ushort_t AT[BM * BK];
    __shared__ __align__(16) ushort_t BT[BN * BK];

    int tile = blockIdx.y;
    if (tile >= meta[16]) return;
    int e = meta[32 + 2 * tile];
    int mt = meta[33 + 2 * tile];
    int off = meta[e];
    int cnt = meta[e + 1] - off;
    int m0 = mt * BM;
    int n0 = blockIdx.x * BN;

    int tid = threadIdx.x;
    int lane = tid & 63;
    int w = tid >> 6;
    int wr = w >> 1, wc = w & 1;
    int srow = lane >> 3;
    int schunk = lane & 7;
    int gchunk = schunk ^ srow;

    const ushort_t* Ae = act + (size_t)off * HID;
    const ushort_t* Be = DT + ((size_t)e * IN_DIM + n0) * HID;

    const ushort_t* ap[4];
    const ushort_t* bp[4];
#pragma unroll
    for (int i = 0; i < 4; i++) {
        int r = w * 32 + i * 8 + srow;
        int ar = m0 + r; if (ar >= cnt) ar = cnt - 1;
        ap[i] = Ae + (size_t)ar * HID + gchunk * 8;
        bp[i] = Be + (size_t)r * HID + gchunk * 8;
    }

    f32x4 acc[4][4];
#pragma unroll
    for (int mi = 0; mi < 4; mi++)
#pragma unroll
        for (int ni = 0; ni < 4; ni++) acc[mi][ni] = (f32x4){0.f, 0.f, 0.f, 0.f};

    int r4 = lane & 15;
    int q = lane >> 4;
    int sw7 = r4 & 7;

    for (int k0 = 0; k0 < HID; k0 += BK) {
#pragma unroll
        for (int i = 0; i < 4; i++) {
            int lo = (w * 32 + i * 8) * BK;
            async16(ap[i] + k0, &AT[lo]);
            async16(bp[i] + k0, &BT[lo]);
        }
        __syncthreads();
#pragma unroll
        for (int kk = 0; kk < BK; kk += 32) {
            int c = (kk >> 3) + q;
            int cs = ((c ^ sw7) << 3);
            bf16x8 a[4], b[4];
#pragma unroll
            for (int i = 0; i < 4; i++) {
                a[i] = *(const bf16x8*)&AT[(wr * 64 + i * 16 + r4) * BK + cs];
                b[i] = *(const bf16x8*)&BT[(wc * 64 + i * 16 + r4) * BK + cs];
            }
#pragma unroll
            for (int mi = 0; mi < 4; mi++)
#pragma unroll
                for (int ni = 0; ni < 4; ni++)
                    acc[mi][ni] = __builtin_amdgcn_mfma_f32_16x16x32_bf16(
                        a[mi], b[ni], acc[mi][ni], 0, 0, 0);
        }
        __syncthreads();
    }

#pragma unroll
    for (int mi = 0; mi < 4; mi++) {
#pragma unroll
        for (int r = 0; r < 4; r++) {
            int row_local = wr * 64 + mi * 16 + (lane >> 4) * 4 + r;
            int grow = m0 + row_local;
            if (grow >= cnt) continue;
            int pos = off + grow;
            int tok = stok[pos];
            float wgt = sw[pos];
            float* orow = out + (size_t)tok * IN_DIM + n0 + wc * 64;
#pragma unroll
            for (int ni = 0; ni < 4; ni++)
                atomicAdd(&orow[ni * 16 + (lane & 15)], wgt * acc[mi][ni][r]);
        }
    }
}

// ---------------------------------------------------------------------------
extern "C" void kernel_launch(void* const* d_in, const int* in_sizes, int n_in,
                              void* d_out, int out_size, void* d_ws, size_t ws_size,
                              hipStream_t stream) {
    const float* inp  = (const float*)d_in[0];
    const float* wts  = (const float*)d_in[1];
    const float* up   = (const float*)d_in[2];
    const float* gate = (const float*)d_in[3];
    const float* down = (const float*)d_in[4];
    const int*   sel  = (const int*)d_in[5];
    float* out = (float*)d_out;

    char* ws = (char*)d_ws;
    ushort_t* inp_bf  = (ushort_t*)(ws);
    ushort_t* up_bf   = (ushort_t*)(ws + 16777216);
    ushort_t* gate_bf = (ushort_t*)(ws + 50331648);
    ushort_t* down_bf = (ushort_t*)(ws + 83886080);
    ushort_t* act     = (ushort_t*)(ws + 117440512);
    int*      stok    = (int*)(ws + 184549376);
    float*    sw      = (float*)(ws + 184614912);
    int*      meta    = (int*)(ws + 184680448);

    hipMemsetAsync(d_out, 0, (size_t)SEQ * IN_DIM * sizeof(float), stream);

    cast_bf16_kernel<<<(SEQ * IN_DIM) / 1024, 256, 0, stream>>>(inp, inp_bf, SEQ * IN_DIM);
    cast_bf16_kernel<<<(NEXP * HID * IN_DIM) / 1024, 256, 0, stream>>>(up, up_bf, NEXP * HID * IN_DIM);
    cast_bf16_kernel<<<(NEXP * HID * IN_DIM) / 1024, 256, 0, stream>>>(gate, gate_bf, NEXP * HID * IN_DIM);
    transpose_cast_kernel<<<dim3(IN_DIM / 32, HID / 32, NEXP), 256, 0, stream>>>(down, down_bf);
    route_kernel<<<1, 256, 0, stream>>>(sel, wts, meta, stok, sw);
    gemm1_kernel<<<dim3(HID / BN, MAX_TILES, 1), 256, 0, stream>>>(inp_bf, up_bf, gate_bf, meta, stok, act);
    gemm2_kernel<<<dim3(IN_DIM / BN, MAX_TILES, 1), 256, 0, stream>>>(act, down_bf, meta, stok, sw, out);
}

// Round 3
// 613.337 us; speedup vs baseline: 1.3222x; 1.2397x over previous
//
#include <hip/hip_runtime.h>

// ---------------------------------------------------------------------------
// MoE FFN: SEQ=8192, IN_DIM=1024, HID=2048, 8 experts, topk=2, gelu(tanh) gate
// R3: software-pipelined K-loops (double-buffered LDS, raw s_barrier + fine
// s_waitcnt vmcnt(8) — never a full drain mid-loop), tiles-fastest grid for
// weight-tile L2 sharing, and atomic-free combine (per-slot y buffer + gather
// kernel via inverse routing map). XOR chunk swizzle kept (R2: conflicts = 0).
// ---------------------------------------------------------------------------

#define SEQ 8192
#define IN_DIM 1024
#define HID 2048
#define NEXP 8
#define TOPK 2
#define NSLOT (SEQ * TOPK)

#define BM 128
#define BK 64
#define MAX_TILES 136

typedef unsigned short ushort_t;
typedef __bf16 bf16x8 __attribute__((ext_vector_type(8)));
typedef float f32x4 __attribute__((ext_vector_type(4)));

__device__ __forceinline__ ushort_t f2bf(float f) {
    union { float f; unsigned u; } v;
    v.f = f;
    unsigned r = v.u + 0x7FFFu + ((v.u >> 16) & 1u);
    return (ushort_t)(r >> 16);
}

__device__ __forceinline__ float gelu_tanh(float x) {
    float u = 0.7978845608028654f * x * (1.0f + 0.044715f * x * x);
    return x / (1.0f + __expf(-2.0f * u));
}

__device__ __forceinline__ void async16(const void* g, void* l) {
    __builtin_amdgcn_global_load_lds(
        (const __attribute__((address_space(1))) unsigned int*)g,
        (__attribute__((address_space(3))) unsigned int*)l, 16, 0, 0);
}

// pipeline barriers (CK idiom): wait for all-but-8 outstanding vmem (the
// just-issued prefetch), then barrier. Never vmcnt(0) mid-loop.
__device__ __forceinline__ void wait8_barrier() {
    asm volatile("s_waitcnt vmcnt(8)\ns_barrier" ::: "memory");
}
__device__ __forceinline__ void wait0_barrier() {
    asm volatile("s_waitcnt vmcnt(0)\ns_barrier" ::: "memory");
}
__device__ __forceinline__ void lds_barrier() {
    asm volatile("s_waitcnt lgkmcnt(0)\ns_barrier" ::: "memory");
}

// ---------------------------------------------------------------------------
__global__ void cast_bf16_kernel(const float* __restrict__ in,
                                 ushort_t* __restrict__ out, int n) {
    int i = (blockIdx.x * blockDim.x + threadIdx.x) * 4;
    if (i >= n) return;
    float4 v = *(const float4*)(in + i);
    union { ushort_t u[4]; uint2 v; } o;
    o.u[0] = f2bf(v.x); o.u[1] = f2bf(v.y);
    o.u[2] = f2bf(v.z); o.u[3] = f2bf(v.w);
    *(uint2*)(out + i) = o.v;
}

// down_proj [8][2048][1024] fp32 -> [8][1024][2048] bf16
__global__ void transpose_cast_kernel(const float* __restrict__ in,
                                      ushort_t* __restrict__ out) {
    __shared__ float tile[32][33];
    int e = blockIdx.z;
    int d0 = blockIdx.x * 32, h0 = blockIdx.y * 32;
    int tx = threadIdx.x & 31, ty = threadIdx.x >> 5;
    const float* src = in + (size_t)e * HID * IN_DIM;
    for (int j = 0; j < 32; j += 8)
        tile[ty + j][tx] = src[(size_t)(h0 + ty + j) * IN_DIM + d0 + tx];
    __syncthreads();
    ushort_t* dst = out + (size_t)e * IN_DIM * HID;
    for (int j = 0; j < 32; j += 8)
        dst[(size_t)(d0 + ty + j) * HID + h0 + tx] = f2bf(tile[tx][ty + j]);
}

// ---------------------------------------------------------------------------
__global__ void route_kernel(const int* __restrict__ sel,
                             const float* __restrict__ wts,
                             int* __restrict__ meta,
                             int* __restrict__ stok,
                             int* __restrict__ sinv) {
    __shared__ int lc[256][NEXP];
    __shared__ int tot[NEXP];
    __shared__ int s_off[NEXP + 1];
    int t = threadIdx.x;
    int cnt[NEXP];
#pragma unroll
    for (int e = 0; e < NEXP; e++) cnt[e] = 0;
    int base = t * (NSLOT / 256);
    for (int i = 0; i < NSLOT / 256; i++) cnt[sel[base + i]]++;
#pragma unroll
    for (int e = 0; e < NEXP; e++) lc[t][e] = cnt[e];
    __syncthreads();
    if (t < NEXP) {
        int run = 0;
        for (int i = 0; i < 256; i++) { int v = lc[i][t]; lc[i][t] = run; run += v; }
        tot[t] = run;
    }
    __syncthreads();
    if (t == 0) {
        int o = 0;
        for (int e = 0; e < NEXP; e++) { s_off[e] = o; o += tot[e]; }
        s_off[NEXP] = o;
        for (int e = 0; e <= NEXP; e++) meta[e] = s_off[e];
        int nt = 0;
        for (int e = 0; e < NEXP; e++) {
            int c = s_off[e + 1] - s_off[e];
            int m = (c + BM - 1) / BM;
            for (int i = 0; i < m; i++) { meta[32 + 2 * nt] = e; meta[33 + 2 * nt] = i; nt++; }
        }
        meta[16] = nt;
    }
    __syncthreads();
    int cur[NEXP];
#pragma unroll
    for (int e = 0; e < NEXP; e++) cur[e] = s_off[e] + lc[t][e];
    for (int i = 0; i < NSLOT / 256; i++) {
        int slot = base + i;
        int e = sel[slot];
        int pos = cur[e]++;
        stok[pos] = slot >> 1;
        sinv[slot] = pos;
    }
}

// ---------------------------------------------------------------------------
// GEMM1: act = gelu(x@Wg^T) * (x@Wu^T). Tile 128(M) x 64(N), BK=64, dbuf.
// grid.x = tile (m/expert), grid.y = n-block (16 of 32) -> consecutive blocks
// share the same U/G weight tile in L2.
__global__ __launch_bounds__(256) void gemm1_kernel(
    const ushort_t* __restrict__ X,
    const ushort_t* __restrict__ U,
    const ushort_t* __restrict__ G,
    const int* __restrict__ meta,
    const int* __restrict__ stok,
    ushort_t* __restrict__ act) {
    __shared__ __align__(16) ushort_t XT[2][BM * BK];   // 32 KB
    __shared__ __align__(16) ushort_t UT[2][64 * BK];   // 16 KB
    __shared__ __align__(16) ushort_t GT[2][64 * BK];   // 16 KB
    __shared__ int s_tok[BM];

    int tile = blockIdx.x;
    if (tile >= meta[16]) return;
    int e = meta[32 + 2 * tile];
    int mt = meta[33 + 2 * tile];
    int off = meta[e];
    int cnt = meta[e + 1] - off;
    int m0 = mt * BM;
    int n0 = blockIdx.y * 64;

    int tid = threadIdx.x;
    if (tid < BM) {
        int r = m0 + tid;
        if (r >= cnt) r = cnt - 1;
        s_tok[tid] = stok[off + r];
    }
    __syncthreads();   // also drains vmcnt -> clean baseline for the pipeline

    int lane = tid & 63;
    int w = tid >> 6;
    int wr = w >> 1, wc = w & 1;
    int srow = lane >> 3;
    int schunk = lane & 7;
    int gchunk = schunk ^ srow;      // swizzled source chunk (R2-verified)

    const ushort_t* Ue = U + ((size_t)e * HID + n0) * IN_DIM;
    const ushort_t* Ge = G + ((size_t)e * HID + n0) * IN_DIM;

    const ushort_t* xp[4];
    const ushort_t* up2[2];
    const ushort_t* gp2[2];
#pragma unroll
    for (int i = 0; i < 4; i++) {
        int r = w * 32 + i * 8 + srow;
        xp[i] = X + (size_t)s_tok[r] * IN_DIM + gchunk * 8;
    }
#pragma unroll
    for (int i = 0; i < 2; i++) {
        int r = w * 16 + i * 8 + srow;
        up2[i] = Ue + (size_t)r * IN_DIM + gchunk * 8;
        gp2[i] = Ge + (size_t)r * IN_DIM + gchunk * 8;
    }

    f32x4 accH[4][2], accG[4][2];
#pragma unroll
    for (int mi = 0; mi < 4; mi++)
#pragma unroll
        for (int ni = 0; ni < 2; ni++) {
            accH[mi][ni] = (f32x4){0.f, 0.f, 0.f, 0.f};
            accG[mi][ni] = (f32x4){0.f, 0.f, 0.f, 0.f};
        }

    int r4 = lane & 15;
    int q = lane >> 4;
    int sw7 = r4 & 7;

#define G1_ISSUE(s)                                                        \
    {                                                                      \
        int _b = (s) & 1;                                                  \
        int _k0 = (s) * BK;                                                \
        _Pragma("unroll")                                                  \
        for (int i = 0; i < 4; i++)                                        \
            async16(xp[i] + _k0, &XT[_b][(w * 32 + i * 8) * BK]);          \
        _Pragma("unroll")                                                  \
        for (int i = 0; i < 2; i++) {                                      \
            async16(up2[i] + _k0, &UT[_b][(w * 16 + i * 8) * BK]);         \
            async16(gp2[i] + _k0, &GT[_b][(w * 16 + i * 8) * BK]);         \
        }                                                                  \
    }

#define G1_COMPUTE(s)                                                      \
    {                                                                      \
        int _b = (s) & 1;                                                  \
        _Pragma("unroll")                                                  \
        for (int kk = 0; kk < BK; kk += 32) {                              \
            int c = (kk >> 3) + q;                                         \
            int cs = ((c ^ sw7) << 3);                                     \
            bf16x8 a[4], bu[2], bg[2];                                     \
            _Pragma("unroll")                                              \
            for (int i = 0; i < 4; i++)                                    \
                a[i] = *(const bf16x8*)&XT[_b][(wr * 64 + i * 16 + r4) * BK + cs]; \
            _Pragma("unroll")                                              \
            for (int i = 0; i < 2; i++) {                                  \
                bu[i] = *(const bf16x8*)&UT[_b][(wc * 32 + i * 16 + r4) * BK + cs]; \
                bg[i] = *(const bf16x8*)&GT[_b][(wc * 32 + i * 16 + r4) * BK + cs]; \
            }                                                              \
            _Pragma("unroll")                                              \
            for (int mi = 0; mi < 4; mi++)                                 \
                _Pragma("unroll")                                          \
                for (int ni = 0; ni < 2; ni++) {                           \
                    accH[mi][ni] = __builtin_amdgcn_mfma_f32_16x16x32_bf16(\
                        a[mi], bu[ni], accH[mi][ni], 0, 0, 0);             \
                    accG[mi][ni] = __builtin_amdgcn_mfma_f32_16x16x32_bf16(\
                        a[mi], bg[ni], accG[mi][ni], 0, 0, 0);             \
                }                                                          \
        }                                                                  \
    }

    const int NK = IN_DIM / BK;   // 16
    G1_ISSUE(0);
    for (int s = 0; s < NK - 1; s++) {
        G1_ISSUE(s + 1);          // 8 loads -> outstanding
        wait8_barrier();          // stage s landed in LDS (all waves)
        G1_COMPUTE(s);
        lds_barrier();            // all reads of buf s done before reuse
    }
    wait0_barrier();
    G1_COMPUTE(NK - 1);

#pragma unroll
    for (int mi = 0; mi < 4; mi++) {
#pragma unroll
        for (int r = 0; r < 4; r++) {
            int row_local = wr * 64 + mi * 16 + q * 4 + r;
            int grow = m0 + row_local;
            if (grow >= cnt) continue;
            size_t orow = (size_t)(off + grow) * HID + n0 + wc * 32;
#pragma unroll
            for (int ni = 0; ni < 2; ni++) {
                float h = accH[mi][ni][r];
                float g = accG[mi][ni][r];
                act[orow + ni * 16 + r4] = f2bf(gelu_tanh(g) * h);
            }
        }
    }
}

// ---------------------------------------------------------------------------
// GEMM2: y[pos] = act[pos] @ Wd (per-slot raw output, no weights, no atomics)
// Tile 128x128, BK=64, dbuf. grid.x = tile, grid.y = n-block (8).
__global__ __launch_bounds__(256) void gemm2_kernel(
    const ushort_t* __restrict__ act,
    const ushort_t* __restrict__ DT,
    const int* __restrict__ meta,
    float* __restrict__ y) {            // [NSLOT][IN_DIM] fp32
    __shared__ __align__(16) ushort_t AT[2][BM * BK];   // 32 KB
    __shared__ __align__(16) ushort_t BT[2][BM * BK];   // 32 KB

    int tile = blockIdx.x;
    if (tile >= meta[16]) return;
    int e = meta[32 + 2 * tile];
    int mt = meta[33 + 2 * tile];
    int off = meta[e];
    int cnt = meta[e + 1] - off;
    int m0 = mt * BM;
    int n0 = blockIdx.y * 128;

    int tid = threadIdx.x;
    int lane = tid & 63;
    int w = tid >> 6;
    int wr = w >> 1, wc = w & 1;
    int srow = lane >> 3;
    int schunk = lane & 7;
    int gchunk = schunk ^ srow;

    const ushort_t* Ae = act + (size_t)off * HID;
    const ushort_t* Be = DT + ((size_t)e * IN_DIM + n0) * HID;

    const ushort_t* ap[4];
    const ushort_t* bp[4];
#pragma unroll
    for (int i = 0; i < 4; i++) {
        int r = w * 32 + i * 8 + srow;
        int ar = m0 + r; if (ar >= cnt) ar = cnt - 1;
        ap[i] = Ae + (size_t)ar * HID + gchunk * 8;
        bp[i] = Be + (size_t)r * HID + gchunk * 8;
    }

    f32x4 acc[4][4];
#pragma unroll
    for (int mi = 0; mi < 4; mi++)
#pragma unroll
        for (int ni = 0; ni < 4; ni++) acc[mi][ni] = (f32x4){0.f, 0.f, 0.f, 0.f};

    int r4 = lane & 15;
    int q = lane >> 4;
    int sw7 = r4 & 7;

#define G2_ISSUE(s)                                                        \
    {                                                                      \
        int _b = (s) & 1;                                                  \
        int _k0 = (s) * BK;                                                \
        _Pragma("unroll")                                                  \
        for (int i = 0; i < 4; i++) {                                      \
            async16(ap[i] + _k0, &AT[_b][(w * 32 + i * 8) * BK]);          \
            async16(bp[i] + _k0, &BT[_b][(w * 32 + i * 8) * BK]);          \
        }                                                                  \
    }

#define G2_COMPUTE(s)                                                      \
    {                                                                      \
        int _b = (s) & 1;                                                  \
        _Pragma("unroll")                                                  \
        for (int kk = 0; kk < BK; kk += 32) {                              \
            int c = (kk >> 3) + q;                                         \
            int cs = ((c ^ sw7) << 3);                                     \
            bf16x8 a[4], b[4];                                             \
            _Pragma("unroll")                                              \
            for (int i = 0; i < 4; i++) {                                  \
                a[i] = *(const bf16x8*)&AT[_b][(wr * 64 + i * 16 + r4) * BK + cs]; \
                b[i] = *(const bf16x8*)&BT[_b][(wc * 64 + i * 16 + r4) * BK + cs]; \
            }                                                              \
            _Pragma("unroll")                                              \
            for (int mi = 0; mi < 4; mi++)                                 \
                _Pragma("unroll")                                          \
                for (int ni = 0; ni < 4; ni++)                             \
                    acc[mi][ni] = __builtin_amdgcn_mfma_f32_16x16x32_bf16( \
                        a[mi], b[ni], acc[mi][ni], 0, 0, 0);               \
        }                                                                  \
    }

    const int NK = HID / BK;   // 32
    G2_ISSUE(0);
    for (int s = 0; s < NK - 1; s++) {
        G2_ISSUE(s + 1);
        wait8_barrier();
        G2_COMPUTE(s);
        lds_barrier();
    }
    wait0_barrier();
    G2_COMPUTE(NK - 1);

#pragma unroll
    for (int mi = 0; mi < 4; mi++) {
#pragma unroll
        for (int r = 0; r < 4; r++) {
            int row_local = wr * 64 + mi * 16 + q * 4 + r;
            int grow = m0 + row_local;
            if (grow >= cnt) continue;
            float* orow = y + (size_t)(off + grow) * IN_DIM + n0 + wc * 64;
#pragma unroll
            for (int ni = 0; ni < 4; ni++)
                orow[ni * 16 + r4] = acc[mi][ni][r];
        }
    }
}

// ---------------------------------------------------------------------------
// combine: out[tok] = w0*y[sinv[2tok]] + w1*y[sinv[2tok+1]]. One block/token.
__global__ __launch_bounds__(256) void combine_kernel(
    const float* __restrict__ y,
    const float* __restrict__ wts,
    const int* __restrict__ sinv,
    float* __restrict__ out) {
    int tok = blockIdx.x;
    int c = threadIdx.x;              // 256 threads x float4 = 1024 floats
    int p0 = sinv[tok * 2], p1 = sinv[tok * 2 + 1];
    float w0 = wts[tok * 2], w1 = wts[tok * 2 + 1];
    float4 a = *(const float4*)(y + (size_t)p0 * IN_DIM + c * 4);
    float4 b = *(const float4*)(y + (size_t)p1 * IN_DIM + c * 4);
    float4 o;
    o.x = w0 * a.x + w1 * b.x;
    o.y = w0 * a.y + w1 * b.y;
    o.z = w0 * a.z + w1 * b.z;
    o.w = w0 * a.w + w1 * b.w;
    *(float4*)(out + (size_t)tok * IN_DIM + c * 4) = o;
}

// ---------------------------------------------------------------------------
extern "C" void kernel_launch(void* const* d_in, const int* in_sizes, int n_in,
                              void* d_out, int out_size, void* d_ws, size_t ws_size,
                              hipStream_t stream) {
    const float* inp  = (const float*)d_in[0];
    const float* wts  = (const float*)d_in[1];
    const float* up   = (const float*)d_in[2];
    const float* gate = (const float*)d_in[3];
    const float* down = (const float*)d_in[4];
    const int*   sel  = (const int*)d_in[5];
    float* out = (float*)d_out;

    // workspace layout: y (fp32, 64 MB) ALIASES inp_bf/up_bf/part of gate_bf —
    // safe because gemm2 (writes y) is stream-ordered after gemm1 (last reader
    // of inp/up/gate_bf), and casts rewrite them every call.
    char* ws = (char*)d_ws;
    ushort_t* inp_bf  = (ushort_t*)(ws);
    ushort_t* up_bf   = (ushort_t*)(ws + 16777216);
    ushort_t* gate_bf = (ushort_t*)(ws + 50331648);
    ushort_t* down_bf = (ushort_t*)(ws + 83886080);
    ushort_t* act     = (ushort_t*)(ws + 117440512);
    int*      stok    = (int*)(ws + 184549376);
    int*      sinv    = (int*)(ws + 184614912);
    int*      meta    = (int*)(ws + 184680448);
    float*    y       = (float*)(ws);            // 64 MB, aliases bf16 inputs

    cast_bf16_kernel<<<(SEQ * IN_DIM) / 1024, 256, 0, stream>>>(inp, inp_bf, SEQ * IN_DIM);
    cast_bf16_kernel<<<(NEXP * HID * IN_DIM) / 1024, 256, 0, stream>>>(up, up_bf, NEXP * HID * IN_DIM);
    cast_bf16_kernel<<<(NEXP * HID * IN_DIM) / 1024, 256, 0, stream>>>(gate, gate_bf, NEXP * HID * IN_DIM);
    transpose_cast_kernel<<<dim3(IN_DIM / 32, HID / 32, NEXP), 256, 0, stream>>>(down, down_bf);
    route_kernel<<<1, 256, 0, stream>>>(sel, wts, meta, stok, sinv);
    gemm1_kernel<<<dim3(MAX_TILES, HID / 64), 256, 0, stream>>>(inp_bf, up_bf, gate_bf, meta, stok, act);
    gemm2_kernel<<<dim3(MAX_TILES, IN_DIM / 128), 256, 0, stream>>>(act, down_bf, meta, y);
    combine_kernel<<<SEQ, 256, 0, stream>>>(y, wts, sinv, out);
}